// Round 2
// baseline (670.770 us; speedup 1.0000x reference)
//
#include <hip/hip_runtime.h>
#include <hip/hip_bf16.h>

#define INF38 1e38f
#define SCALE 0.04419417382415922f   // 1/sqrt(512)

__device__ __forceinline__ float bfu(unsigned short u){
  return __uint_as_float(((unsigned int)u) << 16);
}
__device__ __forceinline__ float ldf(const void* p, long i, int isbf){
  if (isbf) return bfu(((const unsigned short*)p)[i]);
  return ((const float*)p)[i];
}
__device__ __forceinline__ void load8(const void* p, long idx, int isbf, float* out){
  if (isbf){
    const unsigned short* u = (const unsigned short*)p + idx;
    uint4 raw = *(const uint4*)u;
    out[0]=bfu(raw.x&0xffff); out[1]=bfu(raw.x>>16);
    out[2]=bfu(raw.y&0xffff); out[3]=bfu(raw.y>>16);
    out[4]=bfu(raw.z&0xffff); out[5]=bfu(raw.z>>16);
    out[6]=bfu(raw.w&0xffff); out[7]=bfu(raw.w>>16);
  } else {
    const float* f = (const float*)p + idx;
    float4 a = *(const float4*)f; float4 b = *(const float4*)(f+4);
    out[0]=a.x; out[1]=a.y; out[2]=a.z; out[3]=a.w;
    out[4]=b.x; out[5]=b.y; out[6]=b.z; out[7]=b.w;
  }
}
__device__ __forceinline__ void stf(void* p, long i, float x, int isbf){
  if (isbf){
    unsigned int b = __float_as_uint(x);
    unsigned int r = (b + 0x7fffu + ((b>>16)&1u)) >> 16;   // RNE f32->bf16
    ((unsigned short*)p)[i] = (unsigned short)r;
  } else ((float*)p)[i] = x;
}

// ---------------- dtype probe ----------------
// Reads the first 2048 elements of `queries` as bf16 (always within the
// buffer). True-bf16 N(0,1) data: ~99% of |x| in (1e-3,16). f32 data read as
// bf16: the low half-words have random exponents -> ~55% in range.
__global__ void probe_dtype(const unsigned short* q, int* flag){
  const int t = threadIdx.x;
  int good = 0;
  for (int i = t; i < 2048; i += 256){
    float ax = fabsf(bfu(q[i]));
    good += (ax > 1e-3f && ax < 16.f) ? 1 : 0;
  }
  __shared__ int sh[256];
  sh[t] = good; __syncthreads();
  for (int st = 128; st > 0; st >>= 1){ if (t < st) sh[t] += sh[t+st]; __syncthreads(); }
  if (t == 0) *flag = (sh[0] >= 1536) ? 1 : 0;   // >=75% in-range => bf16
}

// ---------------- QKV projection ----------------
// C[8192,512] = A[8192,512] @ W[512,512] + b for mat in {q,k,v}.
// q,k written TRANSPOSED per head: dst[(b*512+col)*1024 + sk]; v natural.
__global__ __launch_bounds__(256) void proj_gemm(
    const void* queries, const void* keys,
    const void* Wq, const void* bq, const void* Wk, const void* bk,
    const void* Wv, const void* bv,
    float* qt, float* kt, float* vbuf, const int* flagp)
{
  const int isbf = *flagp;
  const int mat = blockIdx.z;
  const void* A; const void* W; const void* bias;
  if (mat == 0){ A = queries; W = Wq; bias = bq; }
  else if (mat == 1){ A = keys; W = Wk; bias = bk; }
  else { A = keys; W = Wv; bias = bv; }
  const int row0 = blockIdx.y*128, col0 = blockIdx.x*128;
  __shared__ float As[16][128];   // [kk][row]  (A-tile transposed)
  __shared__ float Ws[16][128];   // [kk][col]
  const int t = threadIdx.x, tx = t & 15, ty = t >> 4;
  float acc[8][8];
  #pragma unroll
  for (int i=0;i<8;++i){
    #pragma unroll
    for (int j=0;j<8;++j) acc[i][j] = 0.f;
  }
  const int ar = t >> 1, ak0 = (t & 1)*8;
  const int wk = t >> 4, wc0 = (t & 15)*8;
  for (int k0 = 0; k0 < 512; k0 += 16){
    __syncthreads();
    float tmp[8];
    load8(A, (long)(row0+ar)*512 + k0 + ak0, isbf, tmp);
    #pragma unroll
    for (int i=0;i<8;++i) As[ak0+i][ar] = tmp[i];
    load8(W, (long)(k0+wk)*512 + col0 + wc0, isbf, tmp);
    #pragma unroll
    for (int i=0;i<8;++i) Ws[wk][wc0+i] = tmp[i];
    __syncthreads();
    #pragma unroll
    for (int kk=0;kk<16;++kk){
      float a[8], w[8];
      *(float4*)&a[0] = *(const float4*)&As[kk][ty*8];
      *(float4*)&a[4] = *(const float4*)&As[kk][ty*8+4];
      *(float4*)&w[0] = *(const float4*)&Ws[kk][tx*8];
      *(float4*)&w[4] = *(const float4*)&Ws[kk][tx*8+4];
      #pragma unroll
      for (int i=0;i<8;++i){
        #pragma unroll
        for (int j=0;j<8;++j) acc[i][j] += a[i]*w[j];
      }
    }
  }
  float b8[8];
  #pragma unroll
  for (int j=0;j<8;++j) b8[j] = ldf(bias, col0 + tx*8 + j, isbf);
  if (mat < 2){
    float* dst = (mat == 0) ? qt : kt;
    #pragma unroll
    for (int i=0;i<8;++i){
      int r = row0 + ty*8 + i;
      int bb = r >> 10, sk = r & 1023;
      #pragma unroll
      for (int j=0;j<8;++j){
        int col = col0 + tx*8 + j;
        dst[(((long)(bb*512 + col)) << 10) + sk] = acc[i][j] + b8[j];
      }
    }
  } else {
    #pragma unroll
    for (int i=0;i<8;++i){
      long r = row0 + ty*8 + i;
      float* dst = vbuf + r*512 + col0 + tx*8;
      #pragma unroll
      for (int j=0;j<8;++j) dst[j] = acc[i][j] + b8[j];
    }
  }
}

// ---------------- flash attention ----------------
// Block: one (b,h,q-tile of 64). 4x4 micro-tiles, online softmax in regs,
// row stats shared across the 16-lane tx-crew via shfl_xor. Ks reused as Pt.
__global__ __launch_bounds__(256) void attn_kernel(
    const float* qt, const float* kt, const float* vbuf,
    const void* pres_q, const void* pres_k,
    float* o1, const int* flagp)
{
  const int isbf = *flagp;
  const int b = blockIdx.z, h = blockIdx.y;
  const int q0 = blockIdx.x*64;
  const int t = threadIdx.x, tx = t & 15, ty = t >> 4;
  __shared__ float Qs[64][68];   // [dd][qi]
  __shared__ float Ks[64][68];   // [dd][kj]  -> reused as Pt[kj][qi]
  __shared__ float Vs[64][68];   // [kj][dd]
  __shared__ float pq_s[64], pk_s[64];
  {
    const int dd = t >> 2, c0 = (t & 3)*16;
    const float* src = qt + (((long)((b*8+h)*64 + dd)) << 10) + q0 + c0;
    #pragma unroll
    for (int u=0;u<4;++u) *(float4*)&Qs[dd][c0+4*u] = ((const float4*)src)[u];
  }
  if (t < 64) pq_s[t] = ldf(pres_q, b*1024 + q0 + t, isbf);
  float m_st[4], l_st[4], o_acc[4][4];
  #pragma unroll
  for (int i=0;i<4;++i){
    m_st[i] = -INFINITY; l_st[i] = 0.f;
    #pragma unroll
    for (int j=0;j<4;++j) o_acc[i][j] = 0.f;
  }
  for (int k0 = 0; k0 < 1024; k0 += 64){
    __syncthreads();                       // prev PV reads done
    {
      const int dd = t >> 2, c0 = (t & 3)*16;
      const float* srcK = kt + (((long)((b*8+h)*64 + dd)) << 10) + k0 + c0;
      #pragma unroll
      for (int u=0;u<4;++u) *(float4*)&Ks[dd][c0+4*u] = ((const float4*)srcK)[u];
      const float* srcV = vbuf + ((long)(b*1024 + k0 + dd))*512 + h*64 + c0;
      #pragma unroll
      for (int u=0;u<4;++u) *(float4*)&Vs[dd][c0+4*u] = ((const float4*)srcV)[u];
    }
    if (t < 64) pk_s[t] = ldf(pres_k, b*1024 + k0 + t, isbf);
    __syncthreads();
    // S = Q K^T (4x4 per thread)
    float s[4][4];
    #pragma unroll
    for (int i=0;i<4;++i){
      #pragma unroll
      for (int j=0;j<4;++j) s[i][j] = 0.f;
    }
    for (int dd = 0; dd < 64; ++dd){
      float4 a4 = *(const float4*)&Qs[dd][ty*4];
      float4 k4 = *(const float4*)&Ks[dd][tx*4];
      float av[4] = {a4.x, a4.y, a4.z, a4.w};
      float kv[4] = {k4.x, k4.y, k4.z, k4.w};
      #pragma unroll
      for (int i=0;i<4;++i){
        #pragma unroll
        for (int j=0;j<4;++j) s[i][j] += av[i]*kv[j];
      }
    }
    // masking (exact reference formula) + online softmax
    float pk4[4];
    #pragma unroll
    for (int j=0;j<4;++j) pk4[j] = pk_s[tx*4 + j];
    #pragma unroll
    for (int i=0;i<4;++i){
      float pq = pq_s[ty*4 + i];
      #pragma unroll
      for (int j=0;j<4;++j){
        float sv = s[i][j]*SCALE;
        sv = pq*sv - (1.f - pq)*INF38;
        sv = pk4[j]*sv - (1.f - pk4[j])*INF38;
        s[i][j] = sv;
      }
    }
    #pragma unroll
    for (int i=0;i<4;++i){
      float mloc = fmaxf(fmaxf(s[i][0], s[i][1]), fmaxf(s[i][2], s[i][3]));
      #pragma unroll
      for (int msk=1; msk<16; msk<<=1) mloc = fmaxf(mloc, __shfl_xor(mloc, msk));
      float mn = fmaxf(m_st[i], mloc);
      float lloc = 0.f;
      #pragma unroll
      for (int j=0;j<4;++j){ s[i][j] = __expf(s[i][j] - mn); lloc += s[i][j]; }
      #pragma unroll
      for (int msk=1; msk<16; msk<<=1) lloc += __shfl_xor(lloc, msk);
      float alpha = __expf(m_st[i] - mn);
      l_st[i] = l_st[i]*alpha + lloc;
      m_st[i] = mn;
      #pragma unroll
      for (int j=0;j<4;++j) o_acc[i][j] *= alpha;
    }
    __syncthreads();                       // Ks reads done -> reuse as Pt
    #pragma unroll
    for (int j=0;j<4;++j){
      float4 w = make_float4(s[0][j], s[1][j], s[2][j], s[3][j]);
      *(float4*)&Ks[tx*4 + j][ty*4] = w;   // Pt[kj][qi]
    }
    __syncthreads();
    // O += P V
    for (int kj = 0; kj < 64; ++kj){
      float4 p4 = *(const float4*)&Ks[kj][ty*4];
      float4 v4 = *(const float4*)&Vs[kj][tx*4];
      float pv[4] = {p4.x, p4.y, p4.z, p4.w};
      float vv[4] = {v4.x, v4.y, v4.z, v4.w};
      #pragma unroll
      for (int i=0;i<4;++i){
        #pragma unroll
        for (int j=0;j<4;++j) o_acc[i][j] += pv[i]*vv[j];
      }
    }
  }
  // epilogue: o = qh + A V   (A = P/l)
  #pragma unroll
  for (int i=0;i<4;++i){
    float inv = 1.f / l_st[i];
    int qi = q0 + ty*4 + i;
    #pragma unroll
    for (int j=0;j<4;++j){
      int dd = tx*4 + j;
      float qh = qt[(((long)((b*8+h)*64 + dd)) << 10) + qi];
      o1[((long)(b*1024 + qi))*512 + h*64 + dd] = qh + o_acc[i][j]*inv;
    }
  }
}

// ---------------- layernorm (wave per row) ----------------
__global__ __launch_bounds__(256) void ln_kernel(
    const float* in, void* outp, int final_store,
    const void* g, const void* bvec, const int* flagp)
{
  const int isbf = *flagp;
  const int row = blockIdx.x*4 + (threadIdx.x >> 6);
  const int lane = threadIdx.x & 63;
  const float* x = in + (long)row*512 + lane*8;
  float v[8];
  *(float4*)&v[0] = *(const float4*)x;
  *(float4*)&v[4] = *(const float4*)(x + 4);
  float sum = 0.f;
  #pragma unroll
  for (int c=0;c<8;++c) sum += v[c];
  #pragma unroll
  for (int msk=1; msk<64; msk<<=1) sum += __shfl_xor(sum, msk);
  float mu = sum * (1.f/512.f);
  float var = 0.f;
  #pragma unroll
  for (int c=0;c<8;++c){ v[c] -= mu; var += v[c]*v[c]; }
  #pragma unroll
  for (int msk=1; msk<64; msk<<=1) var += __shfl_xor(var, msk);
  float rs = rsqrtf(var*(1.f/512.f) + 1e-5f);
  #pragma unroll
  for (int c=0;c<8;++c){
    int col = lane*8 + c;
    float y = v[c]*rs*ldf(g, col, isbf) + ldf(bvec, col, isbf);
    if (final_store) stf(outp, (long)row*512 + col, y, isbf);
    else ((float*)outp)[(long)row*512 + col] = y;
  }
}

// ---------------- output projection: u = t + relu(t @ Wo + bo) ----------------
__global__ __launch_bounds__(256) void out_gemm(
    const float* tbuf, const void* Wo, const void* bo,
    float* ubuf, const int* flagp)
{
  const int isbf = *flagp;
  const int row0 = blockIdx.y*128, col0 = blockIdx.x*128;
  __shared__ float As[16][128];
  __shared__ float Ws[16][128];
  const int t = threadIdx.x, tx = t & 15, ty = t >> 4;
  float acc[8][8];
  #pragma unroll
  for (int i=0;i<8;++i){
    #pragma unroll
    for (int j=0;j<8;++j) acc[i][j] = 0.f;
  }
  const int ar = t >> 1, ak0 = (t & 1)*8;
  const int wk = t >> 4, wc0 = (t & 15)*8;
  for (int k0 = 0; k0 < 512; k0 += 16){
    __syncthreads();
    {
      const float* src = tbuf + (long)(row0+ar)*512 + k0 + ak0;
      float4 x0 = *(const float4*)src, x1 = *(const float4*)(src + 4);
      As[ak0+0][ar]=x0.x; As[ak0+1][ar]=x0.y; As[ak0+2][ar]=x0.z; As[ak0+3][ar]=x0.w;
      As[ak0+4][ar]=x1.x; As[ak0+5][ar]=x1.y; As[ak0+6][ar]=x1.z; As[ak0+7][ar]=x1.w;
    }
    float tmp[8];
    load8(Wo, (long)(k0+wk)*512 + col0 + wc0, isbf, tmp);
    #pragma unroll
    for (int i=0;i<8;++i) Ws[wk][wc0+i] = tmp[i];
    __syncthreads();
    #pragma unroll
    for (int kk=0;kk<16;++kk){
      float a[8], w[8];
      *(float4*)&a[0] = *(const float4*)&As[kk][ty*8];
      *(float4*)&a[4] = *(const float4*)&As[kk][ty*8+4];
      *(float4*)&w[0] = *(const float4*)&Ws[kk][tx*8];
      *(float4*)&w[4] = *(const float4*)&Ws[kk][tx*8+4];
      #pragma unroll
      for (int i=0;i<8;++i){
        #pragma unroll
        for (int j=0;j<8;++j) acc[i][j] += a[i]*w[j];
      }
    }
  }
  float b8[8];
  #pragma unroll
  for (int j=0;j<8;++j) b8[j] = ldf(bo, col0 + tx*8 + j, isbf);
  #pragma unroll
  for (int i=0;i<8;++i){
    long r = row0 + ty*8 + i;
    const float* trow = tbuf + r*512 + col0 + tx*8;
    float* urow = ubuf + r*512 + col0 + tx*8;
    #pragma unroll
    for (int j=0;j<8;++j){
      float u = acc[i][j] + b8[j];
      u = fmaxf(u, 0.f);
      urow[j] = trow[j] + u;
    }
  }
}

extern "C" void kernel_launch(void* const* d_in, const int* in_sizes, int n_in,
                              void* d_out, int out_size, void* d_ws, size_t ws_size,
                              hipStream_t stream)
{
  // ws layout (f32): qt | kt | v | o1 | flag   (4 x 16.78 MB + 4 B = 67.1 MB)
  float* qt = (float*)d_ws;           // q transposed [b,h,dd,sq]; later t (LN0 out)
  float* kt = qt + 4194304;           // k transposed [b,h,dd,sk]
  float* vb = kt + 4194304;           // v natural   [b,sk,512]
  float* o1 = vb + 4194304;           // attention out; later u
  int*  flag = (int*)(o1 + 4194304);

  hipLaunchKernelGGL(probe_dtype, dim3(1), dim3(256), 0, stream,
                     (const unsigned short*)d_in[0], flag);
  hipLaunchKernelGGL(proj_gemm, dim3(4,64,3), dim3(256), 0, stream,
                     d_in[0], d_in[1], d_in[5], d_in[6], d_in[7], d_in[8],
                     d_in[9], d_in[10], qt, kt, vb, flag);
  hipLaunchKernelGGL(attn_kernel, dim3(16,8,8), dim3(256), 0, stream,
                     qt, kt, vb, d_in[2], d_in[3], o1, flag);
  hipLaunchKernelGGL(ln_kernel, dim3(2048), dim3(256), 0, stream,
                     o1, (void*)qt, 0, d_in[13], d_in[14], flag);
  hipLaunchKernelGGL(out_gemm, dim3(4,64), dim3(256), 0, stream,
                     qt, d_in[11], d_in[12], o1, flag);
  hipLaunchKernelGGL(ln_kernel, dim3(2048), dim3(256), 0, stream,
                     o1, d_out, 1, d_in[15], d_in[16], flag);
}

// Round 3
// 287.719 us; speedup vs baseline: 2.3313x; 2.3313x over previous
//
#include <hip/hip_runtime.h>
#include <hip/hip_bf16.h>

typedef __attribute__((ext_vector_type(8))) short short8;
typedef __attribute__((ext_vector_type(4))) float f32x4;

#define INF38 1e38f
#define SCALE 0.04419417382415922f   // 1/sqrt(512)

__device__ __forceinline__ float bfu(unsigned short u){
  return __uint_as_float(((unsigned int)u) << 16);
}
__device__ __forceinline__ unsigned short f2b(float x){
  unsigned int b = __float_as_uint(x);
  return (unsigned short)((b + 0x7fffu + ((b>>16)&1u)) >> 16);   // RNE
}
__device__ __forceinline__ float ldf(const void* p, long i, int isbf){
  if (isbf) return bfu(((const unsigned short*)p)[i]);
  return ((const float*)p)[i];
}
__device__ __forceinline__ void stf(void* p, long i, float x, int isbf){
  if (isbf) ((unsigned short*)p)[i] = f2b(x);
  else ((float*)p)[i] = x;
}
// 8 contiguous elems -> 8 bf16 packed in a uint4 (direct copy if already bf16)
__device__ __forceinline__ uint4 load8bf(const void* p, long idx, int isbf){
  if (isbf) return *(const uint4*)((const unsigned short*)p + idx);
  const float* f = (const float*)p + idx;
  float4 a = *(const float4*)f, b = *(const float4*)(f+4);
  uint4 r;
  r.x = (unsigned)f2b(a.x) | ((unsigned)f2b(a.y)<<16);
  r.y = (unsigned)f2b(a.z) | ((unsigned)f2b(a.w)<<16);
  r.z = (unsigned)f2b(b.x) | ((unsigned)f2b(b.y)<<16);
  r.w = (unsigned)f2b(b.z) | ((unsigned)f2b(b.w)<<16);
  return r;
}

// ---------------- dtype probe (bf16 vs f32 input buffers) ----------------
__global__ void probe_dtype(const unsigned short* q, int* flag){
  const int t = threadIdx.x;
  int good = 0;
  for (int i = t; i < 2048; i += 256){
    float ax = fabsf(bfu(q[i]));
    good += (ax > 1e-3f && ax < 16.f) ? 1 : 0;
  }
  __shared__ int sh[256];
  sh[t] = good; __syncthreads();
  for (int st = 128; st > 0; st >>= 1){ if (t < st) sh[t] += sh[t+st]; __syncthreads(); }
  if (t == 0) *flag = (sh[0] >= 1536) ? 1 : 0;
}

// ---------------- weight transpose: wt[n][k] = W[k][n], bf16 ----------------
__global__ __launch_bounds__(256) void prep_w(
    const void* Wq, const void* Wk, const void* Wv, const void* Wo,
    unsigned short* wt, const int* flagp)
{
  const int isbf = *flagp;
  const int m = blockIdx.z;
  const void* W = (m==0)?Wq:(m==1)?Wk:(m==2)?Wv:Wo;
  unsigned short* dst = wt + (long)m*262144;
  __shared__ unsigned short tile[64][72];
  const int t = threadIdx.x;
  const int n0 = blockIdx.x*64, k0 = blockIdx.y*64;
  {
    int r = t>>2, c0 = (t&3)*16;
    uint4 u0 = load8bf(W, (long)(k0+r)*512 + n0 + c0, isbf);
    uint4 u1 = load8bf(W, (long)(k0+r)*512 + n0 + c0 + 8, isbf);
    unsigned short* us0 = (unsigned short*)&u0;
    unsigned short* us1 = (unsigned short*)&u1;
    #pragma unroll
    for (int i=0;i<8;++i) tile[c0+i][r] = us0[i];
    #pragma unroll
    for (int i=0;i<8;++i) tile[c0+8+i][r] = us1[i];
  }
  __syncthreads();
  {
    int n = t>>2, ks = (t&3)*16;
    *(uint4*)(dst + (long)(n0+n)*512 + k0 + ks)     = *(uint4*)&tile[n][ks];
    *(uint4*)(dst + (long)(n0+n)*512 + k0 + ks + 8) = *(uint4*)&tile[n][ks+8];
  }
}

// ---------------- QKV projection (bf16 MFMA) ----------------
// C[8192,512] = A @ W + b. q,k stored natural bf16; v stored [b*8+h][d][sk].
__global__ __launch_bounds__(256) void proj_mfma(
    const void* queries, const void* keys, const unsigned short* wt,
    const void* bq, const void* bk, const void* bv,
    unsigned short* q_bf, unsigned short* k_bf, unsigned short* vt_bf,
    const int* flagp)
{
  const int isbf = *flagp;
  const int mat = blockIdx.z;
  const void* A = (mat==0)? queries : keys;
  const unsigned short* Wt = wt + (long)mat*262144;
  const void* bias = (mat==0)?bq:(mat==1)?bk:bv;
  const int row0 = blockIdx.y*128, col0 = blockIdx.x*128;
  __shared__ unsigned short As[128][40];   // [m][k], pad 32->40
  __shared__ unsigned short Ws[128][40];   // [n][k]
  const int t = threadIdx.x;
  const int lane = t & 63, wid = t >> 6;
  const int ln = lane & 15, quad = lane >> 4;
  const int wy = wid >> 1, wx = wid & 1;
  f32x4 acc[4][4];
  #pragma unroll
  for (int i=0;i<4;++i){
    #pragma unroll
    for (int j=0;j<4;++j) acc[i][j] = (f32x4){0.f,0.f,0.f,0.f};
  }
  const int sr = t>>1, sk0 = (t&1)*16;
  for (int k0=0;k0<512;k0+=32){
    __syncthreads();
    {
      uint4 u0 = load8bf(A, (long)(row0+sr)*512 + k0 + sk0, isbf);
      uint4 u1 = load8bf(A, (long)(row0+sr)*512 + k0 + sk0 + 8, isbf);
      *(uint4*)&As[sr][sk0]   = u0;
      *(uint4*)&As[sr][sk0+8] = u1;
      uint4 w0 = *(const uint4*)(Wt + (long)(col0+sr)*512 + k0 + sk0);
      uint4 w1 = *(const uint4*)(Wt + (long)(col0+sr)*512 + k0 + sk0 + 8);
      *(uint4*)&Ws[sr][sk0]   = w0;
      *(uint4*)&Ws[sr][sk0+8] = w1;
    }
    __syncthreads();
    short8 a[4], b[4];
    #pragma unroll
    for (int mt=0;mt<4;++mt) a[mt] = *(const short8*)&As[wy*64+mt*16+ln][quad*8];
    #pragma unroll
    for (int nt=0;nt<4;++nt) b[nt] = *(const short8*)&Ws[wx*64+nt*16+ln][quad*8];
    #pragma unroll
    for (int mt=0;mt<4;++mt){
      #pragma unroll
      for (int nt=0;nt<4;++nt)
        acc[mt][nt] = __builtin_amdgcn_mfma_f32_16x16x32_bf16(a[mt], b[nt], acc[mt][nt], 0,0,0);
    }
  }
  float bias_v[4];
  #pragma unroll
  for (int nt=0;nt<4;++nt) bias_v[nt] = ldf(bias, col0 + wx*64 + nt*16 + ln, isbf);
  if (mat < 2){
    unsigned short* dst = (mat==0)? q_bf : k_bf;
    #pragma unroll
    for (int mt=0;mt<4;++mt){
      int row = row0 + wy*64 + mt*16 + quad*4;
      #pragma unroll
      for (int nt=0;nt<4;++nt){
        int col = col0 + wx*64 + nt*16 + ln;
        #pragma unroll
        for (int r=0;r<4;++r)
          dst[(long)(row+r)*512 + col] = f2b(acc[mt][nt][r] + bias_v[nt]);
      }
    }
  } else {
    #pragma unroll
    for (int mt=0;mt<4;++mt){
      int row = row0 + wy*64 + mt*16 + quad*4;   // token base, 4-aligned
      int bb = row >> 10, sk = row & 1023;
      #pragma unroll
      for (int nt=0;nt<4;++nt){
        int col = col0 + wx*64 + nt*16 + ln;
        int h = col >> 6, dd = col & 63;
        uint2 pk2; unsigned short* pp = (unsigned short*)&pk2;
        #pragma unroll
        for (int r=0;r<4;++r) pp[r] = f2b(acc[mt][nt][r] + bias_v[nt]);
        *(uint2*)(vt_bf + (((long)((bb*8+h)*64+dd)) << 10) + sk) = pk2;
      }
    }
  }
}

// ---------------- flash attention (bf16 MFMA) ----------------
// Block = one (b,h,64-q-tile). 4 waves, each a 16-q strip. P LDS round-trip.
__global__ __launch_bounds__(256) void attn_mfma(
    const unsigned short* q_bf, const unsigned short* k_bf, const unsigned short* vt_bf,
    const void* pres_q, const void* pres_k, float* o1, const int* flagp)
{
  const int isbf = *flagp;
  const int b = blockIdx.z, h = blockIdx.y, q0 = blockIdx.x*64;
  const int t = threadIdx.x;
  const int lane = t&63, wid = t>>6, ln = lane&15, quad = lane>>4;
  __shared__ unsigned short Qs[64][72];   // [q][d]
  __shared__ unsigned short Ks[64][72];   // [key][d]
  __shared__ unsigned short Vt[64][72];   // [d][key]
  __shared__ unsigned short Ps[64][72];   // [q][key] bf16 probs
  __shared__ float pq_s[64], pk_s[64];
  {
    int tok = t>>2, ds = (t&3)*16;
    const unsigned short* src = q_bf + (long)(b*1024 + q0 + tok)*512 + h*64 + ds;
    *(uint4*)&Qs[tok][ds]   = *(const uint4*)src;
    *(uint4*)&Qs[tok][ds+8] = *(const uint4*)(src+8);
  }
  if (t < 64) pq_s[t] = ldf(pres_q, (long)b*1024 + q0 + t, isbf);
  f32x4 oacc[4];
  #pragma unroll
  for (int dt=0;dt<4;++dt) oacc[dt] = (f32x4){0.f,0.f,0.f,0.f};
  float m_st[4], l_st[4];
  #pragma unroll
  for (int r=0;r<4;++r){ m_st[r] = -INFINITY; l_st[r] = 0.f; }

  for (int k0=0;k0<1024;k0+=64){
    __syncthreads();                      // prev PV done with Vt/Ps
    {
      int tok = t>>2, ds = (t&3)*16;
      const unsigned short* sk = k_bf + (long)(b*1024 + k0 + tok)*512 + h*64 + ds;
      *(uint4*)&Ks[tok][ds]   = *(const uint4*)sk;
      *(uint4*)&Ks[tok][ds+8] = *(const uint4*)(sk+8);
      const unsigned short* sv = vt_bf + (((long)((b*8+h)*64 + tok)) << 10) + k0 + ds;
      *(uint4*)&Vt[tok][ds]   = *(const uint4*)sv;
      *(uint4*)&Vt[tok][ds+8] = *(const uint4*)(sv+8);
    }
    if (t < 64) pk_s[t] = ldf(pres_k, (long)b*1024 + k0 + t, isbf);
    __syncthreads();
    // S = Q K^T : per wave 16q x 64k
    f32x4 s[4];
    #pragma unroll
    for (int kt=0;kt<4;++kt) s[kt] = (f32x4){0.f,0.f,0.f,0.f};
    short8 aq0 = *(const short8*)&Qs[wid*16+ln][quad*8];
    short8 aq1 = *(const short8*)&Qs[wid*16+ln][32+quad*8];
    #pragma unroll
    for (int kt=0;kt<4;++kt){
      short8 kb0 = *(const short8*)&Ks[kt*16+ln][quad*8];
      short8 kb1 = *(const short8*)&Ks[kt*16+ln][32+quad*8];
      s[kt] = __builtin_amdgcn_mfma_f32_16x16x32_bf16(aq0, kb0, s[kt], 0,0,0);
      s[kt] = __builtin_amdgcn_mfma_f32_16x16x32_bf16(aq1, kb1, s[kt], 0,0,0);
    }
    // mask + online softmax (rows = quad*4+r, cols across ln & kt)
    float pk4[4];
    #pragma unroll
    for (int kt=0;kt<4;++kt) pk4[kt] = pk_s[kt*16+ln];
    float alpha[4];
    #pragma unroll
    for (int r=0;r<4;++r){
      float pq = pq_s[wid*16 + quad*4 + r];
      float sv[4]; float mloc = -INFINITY;
      #pragma unroll
      for (int kt=0;kt<4;++kt){
        float x = s[kt][r]*SCALE;
        x = pq*x - (1.f-pq)*INF38;
        x = pk4[kt]*x - (1.f-pk4[kt])*INF38;
        sv[kt] = x; mloc = fmaxf(mloc, x);
      }
      #pragma unroll
      for (int msk=1; msk<16; msk<<=1) mloc = fmaxf(mloc, __shfl_xor(mloc, msk));
      float mn = fmaxf(m_st[r], mloc);
      float lloc = 0.f;
      #pragma unroll
      for (int kt=0;kt<4;++kt){ sv[kt] = __expf(sv[kt]-mn); lloc += sv[kt]; }
      #pragma unroll
      for (int msk=1; msk<16; msk<<=1) lloc += __shfl_xor(lloc, msk);
      alpha[r] = __expf(m_st[r]-mn);
      l_st[r] = l_st[r]*alpha[r] + lloc;
      m_st[r] = mn;
      #pragma unroll
      for (int kt=0;kt<4;++kt) Ps[wid*16+quad*4+r][kt*16+ln] = f2b(sv[kt]);
    }
    #pragma unroll
    for (int dt=0;dt<4;++dt){
      #pragma unroll
      for (int r=0;r<4;++r) oacc[dt][r] *= alpha[r];
    }
    __syncthreads();                      // Ps visible
    // O += P V : per wave 16q x 64d
    short8 ap0 = *(const short8*)&Ps[wid*16+ln][quad*8];
    short8 ap1 = *(const short8*)&Ps[wid*16+ln][32+quad*8];
    #pragma unroll
    for (int dt=0;dt<4;++dt){
      short8 vb0 = *(const short8*)&Vt[dt*16+ln][quad*8];
      short8 vb1 = *(const short8*)&Vt[dt*16+ln][32+quad*8];
      oacc[dt] = __builtin_amdgcn_mfma_f32_16x16x32_bf16(ap0, vb0, oacc[dt], 0,0,0);
      oacc[dt] = __builtin_amdgcn_mfma_f32_16x16x32_bf16(ap1, vb1, oacc[dt], 0,0,0);
    }
  }
  // epilogue: o = qh + (P V)/l
  #pragma unroll
  for (int r=0;r<4;++r){
    float inv = 1.f / l_st[r];
    int ql = wid*16 + quad*4 + r;
    long base = (long)(b*1024 + q0 + ql)*512 + h*64;
    #pragma unroll
    for (int dt=0;dt<4;++dt){
      float qh = bfu(Qs[ql][dt*16+ln]);
      o1[base + dt*16 + ln] = qh + oacc[dt][r]*inv;
    }
  }
}

// ---------------- layernorm (wave per row) ----------------
// mode 0: write bf16 to internal buffer; mode 1: flagged store to d_out
__global__ __launch_bounds__(256) void ln_kernel(
    const float* in, void* outp, int mode,
    const void* g, const void* bvec, const int* flagp)
{
  const int isbf = *flagp;
  const int row = blockIdx.x*4 + (threadIdx.x >> 6);
  const int lane = threadIdx.x & 63;
  const float* x = in + (long)row*512 + lane*8;
  float v[8];
  *(float4*)&v[0] = *(const float4*)x;
  *(float4*)&v[4] = *(const float4*)(x + 4);
  float sum = 0.f;
  #pragma unroll
  for (int c=0;c<8;++c) sum += v[c];
  #pragma unroll
  for (int msk=1; msk<64; msk<<=1) sum += __shfl_xor(sum, msk);
  float mu = sum * (1.f/512.f);
  float var = 0.f;
  #pragma unroll
  for (int c=0;c<8;++c){ v[c] -= mu; var += v[c]*v[c]; }
  #pragma unroll
  for (int msk=1; msk<64; msk<<=1) var += __shfl_xor(var, msk);
  float rs = rsqrtf(var*(1.f/512.f) + 1e-5f);
  #pragma unroll
  for (int c=0;c<8;++c){
    int col = lane*8 + c;
    float y = v[c]*rs*ldf(g, col, isbf) + ldf(bvec, col, isbf);
    long idx = (long)row*512 + col;
    if (mode) stf(outp, idx, y, isbf);
    else ((unsigned short*)outp)[idx] = f2b(y);
  }
}

// ---------------- out projection: u = t + relu(t @ Wo + bo) ----------------
__global__ __launch_bounds__(256) void out_mfma(
    const unsigned short* t_bf, const unsigned short* Wt, const void* bo,
    float* o1, const int* flagp)
{
  const int isbf = *flagp;
  const int row0 = blockIdx.y*128, col0 = blockIdx.x*128;
  __shared__ unsigned short As[128][40];
  __shared__ unsigned short Ws[128][40];
  const int t = threadIdx.x;
  const int lane = t & 63, wid = t >> 6;
  const int ln = lane & 15, quad = lane >> 4;
  const int wy = wid >> 1, wx = wid & 1;
  f32x4 acc[4][4];
  #pragma unroll
  for (int i=0;i<4;++i){
    #pragma unroll
    for (int j=0;j<4;++j) acc[i][j] = (f32x4){0.f,0.f,0.f,0.f};
  }
  const int sr = t>>1, sk0 = (t&1)*16;
  for (int k0=0;k0<512;k0+=32){
    __syncthreads();
    {
      *(uint4*)&As[sr][sk0]   = *(const uint4*)(t_bf + (long)(row0+sr)*512 + k0 + sk0);
      *(uint4*)&As[sr][sk0+8] = *(const uint4*)(t_bf + (long)(row0+sr)*512 + k0 + sk0 + 8);
      *(uint4*)&Ws[sr][sk0]   = *(const uint4*)(Wt + (long)(col0+sr)*512 + k0 + sk0);
      *(uint4*)&Ws[sr][sk0+8] = *(const uint4*)(Wt + (long)(col0+sr)*512 + k0 + sk0 + 8);
    }
    __syncthreads();
    short8 a[4], b[4];
    #pragma unroll
    for (int mt=0;mt<4;++mt) a[mt] = *(const short8*)&As[wy*64+mt*16+ln][quad*8];
    #pragma unroll
    for (int nt=0;nt<4;++nt) b[nt] = *(const short8*)&Ws[wx*64+nt*16+ln][quad*8];
    #pragma unroll
    for (int mt=0;mt<4;++mt){
      #pragma unroll
      for (int nt=0;nt<4;++nt)
        acc[mt][nt] = __builtin_amdgcn_mfma_f32_16x16x32_bf16(a[mt], b[nt], acc[mt][nt], 0,0,0);
    }
  }
  float bias_v[4];
  #pragma unroll
  for (int nt=0;nt<4;++nt) bias_v[nt] = ldf(bo, col0 + wx*64 + nt*16 + ln, isbf);
  #pragma unroll
  for (int mt=0;mt<4;++mt){
    int row = row0 + wy*64 + mt*16 + quad*4;
    #pragma unroll
    for (int nt=0;nt<4;++nt){
      int col = col0 + wx*64 + nt*16 + ln;
      #pragma unroll
      for (int r=0;r<4;++r){
        long idx = (long)(row+r)*512 + col;
        float u = acc[mt][nt][r] + bias_v[nt];
        u = fmaxf(u, 0.f);
        o1[idx] = bfu(t_bf[idx]) + u;
      }
    }
  }
}

extern "C" void kernel_launch(void* const* d_in, const int* in_sizes, int n_in,
                              void* d_out, int out_size, void* d_ws, size_t ws_size,
                              hipStream_t stream)
{
  // ws (bytes): q_bf 8.4M | k_bf 8.4M | vt_bf 8.4M | t_bf 8.4M | wt 2M | o1 16.8M | flag
  unsigned short* q_bf  = (unsigned short*)d_ws;
  unsigned short* k_bf  = q_bf  + 8192l*512;
  unsigned short* vt_bf = k_bf  + 8192l*512;
  unsigned short* t_bf  = vt_bf + 8192l*512;
  unsigned short* wt    = t_bf  + 8192l*512;
  float* o1   = (float*)(wt + 4l*512*512);
  int*   flag = (int*)(o1 + 8192l*512);

  hipLaunchKernelGGL(probe_dtype, dim3(1), dim3(256), 0, stream,
                     (const unsigned short*)d_in[0], flag);
  hipLaunchKernelGGL(prep_w, dim3(8,8,4), dim3(256), 0, stream,
                     d_in[5], d_in[7], d_in[9], d_in[11], wt, flag);
  hipLaunchKernelGGL(proj_mfma, dim3(4,64,3), dim3(256), 0, stream,
                     d_in[0], d_in[1], wt, d_in[6], d_in[8], d_in[10],
                     q_bf, k_bf, vt_bf, flag);
  hipLaunchKernelGGL(attn_mfma, dim3(16,8,8), dim3(256), 0, stream,
                     q_bf, k_bf, vt_bf, d_in[2], d_in[3], o1, flag);
  hipLaunchKernelGGL(ln_kernel, dim3(2048), dim3(256), 0, stream,
                     o1, (void*)t_bf, 0, d_in[13], d_in[14], flag);
  hipLaunchKernelGGL(out_mfma, dim3(4,64), dim3(256), 0, stream,
                     t_bf, wt + 3l*512*512, d_in[12], o1, flag);
  hipLaunchKernelGGL(ln_kernel, dim3(2048), dim3(256), 0, stream,
                     o1, d_out, 1, d_in[15], d_in[16], flag);
}